// Round 16
// baseline (109.800 us; speedup 1.0000x reference)
//
#include <hip/hip_runtime.h>
#include <math.h>
#include <cstddef>

// AttentionBlock: B=4, L=2048, C=512, H=8, Dk=64
// qkv = x @ W_in + b_in ; per head: causal-softmax(q k^T/8) @ v ; @ W_out + b_out + x

constexpr int B_SZ  = 4;
constexpr int L_SEQ = 2048;
constexpr int C_DIM = 512;
constexpr int H_N   = 8;
constexpr int DK    = 64;
constexpr int N_QKV = 1536;
constexpr int M_ROWS = B_SZ * L_SEQ; // 8192
constexpr float SCALE = 0.125f;
constexpr float DEFER_THR = 8.f;     // defer-max threshold (P <= e^8)

typedef __attribute__((ext_vector_type(4))) float f32x4;
typedef __attribute__((ext_vector_type(8))) short bf16x8;

static __device__ inline ushort f2bf(float f) {
  unsigned u = __builtin_bit_cast(unsigned, f);
  u += 0x7fffu + ((u >> 16) & 1u);
  return (ushort)(u >> 16);
}

typedef __attribute__((address_space(1))) const unsigned int* gas1_t;
typedef __attribute__((address_space(3))) unsigned int* las3_t;
static __device__ inline void gload_lds16(const void* g, void* l) {
  __builtin_amdgcn_global_load_lds((gas1_t)g, (las3_t)l, 16, 0, 0);
}

// K/V tile format (producer-swizzled so LDS-linear staging => conflict-
// balanced ds_read_b128): per (bh, 64-j tile) an 8KB tile of [64 rows][8
// chunks of 16B]; chunk stored at (logical_chunk ^ (row & 7)). K tiles:
// row = j, elem d. V tiles: row = d, elem j.

// ------------------------------------------------- fused prep (1 launch)
__global__ __launch_bounds__(256) void prep_fused(
    const float* __restrict__ x, const float* __restrict__ W_in,
    const float* __restrict__ W_out, ushort* __restrict__ xbf,
    ushort* __restrict__ WinT, ushort* __restrict__ WoutT) {
  const int id = blockIdx.x;
  if (id < 4096) {
    const int i = id * 256 + threadIdx.x;
    const float4 v = reinterpret_cast<const float4*>(x)[i];
    ushort4 o;
    o.x = f2bf(v.x); o.y = f2bf(v.y); o.z = f2bf(v.z); o.w = f2bf(v.w);
    reinterpret_cast<ushort4*>(xbf)[i] = o;
    return;
  }
  __shared__ ushort T[64][65];
  const float* src;
  ushort* dst;
  int R, C, c0, r0;
  if (id < 4096 + 192) {
    const int t = id - 4096;
    src = W_in; dst = WinT; R = C_DIM; C = N_QKV;
    c0 = (t % 24) * 64; r0 = (t / 24) * 64;
  } else {
    const int t = id - 4288;
    src = W_out; dst = WoutT; R = C_DIM; C = C_DIM;
    c0 = (t % 8) * 64; r0 = (t / 8) * 64;
  }
#pragma unroll
  for (int p = 0; p < 16; ++p) {
    const int idx = threadIdx.x + p * 256;
    const int r = idx >> 6, c = idx & 63;
    T[r][c] = f2bf(src[(size_t)(r0 + r) * C + c0 + c]);
  }
  __syncthreads();
#pragma unroll
  for (int p = 0; p < 16; ++p) {
    const int idx = threadIdx.x + p * 256;
    const int r = idx >> 6, c = idx & 63;
    dst[(size_t)(c0 + r) * R + r0 + c] = T[c][r];
  }
}

// -------------------------------------------------- bf16 MFMA GEMM 128x128
template <int EPI>
__global__ __launch_bounds__(256) void gemm_bf16(
    const ushort* __restrict__ A, const ushort* __restrict__ Bt,
    const float* __restrict__ bias, ushort* __restrict__ Qo,
    ushort* __restrict__ Ko, ushort* __restrict__ Vto,
    float* __restrict__ outF, const float* __restrict__ resid,
    int N, int K) {
  __shared__ ushort Al[128 * 32];
  __shared__ ushort Bl[128 * 32];
  const int tid = threadIdx.x;
  const int w = tid >> 6, l = tid & 63;
  const int cc = l & 15, gg = l >> 4;
  const int bm = blockIdx.y * 128, bn = blockIdx.x * 128;
  const int wr = w >> 1, wc = w & 1;
  f32x4 acc[4][4] = {};

  for (int k0 = 0; k0 < K; k0 += 32) {
#pragma unroll
    for (int q = 0; q < 2; ++q) {
      const int cbase = q * 256 + w * 64;
      const int c = cbase + l;
      gload_lds16(A + (size_t)(bm + (c >> 2)) * K + k0 + (c & 3) * 8,
                  &Al[cbase * 8]);
      gload_lds16(Bt + (size_t)(bn + (c >> 2)) * K + k0 + (c & 3) * 8,
                  &Bl[cbase * 8]);
    }
    __syncthreads();
    bf16x8 aF[4], bF[4];
#pragma unroll
    for (int i = 0; i < 4; ++i)
      aF[i] = *reinterpret_cast<const bf16x8*>(
          &Al[(wr * 64 + i * 16 + cc) * 32 + gg * 8]);
#pragma unroll
    for (int j = 0; j < 4; ++j)
      bF[j] = *reinterpret_cast<const bf16x8*>(
          &Bl[(wc * 64 + j * 16 + cc) * 32 + gg * 8]);
#pragma unroll
    for (int i = 0; i < 4; ++i)
#pragma unroll
      for (int j = 0; j < 4; ++j)
        acc[i][j] = __builtin_amdgcn_mfma_f32_16x16x32_bf16(aF[i], bF[j],
                                                            acc[i][j], 0, 0, 0);
    __syncthreads();
  }

  if (EPI == 0) {
#pragma unroll
    for (int j = 0; j < 4; ++j) {
      const int colbase = bn + wc * 64 + j * 16;
      const int h = colbase / 192, rem = colbase % 192;
      const int type = rem / 64, d = (rem % 64) + cc;
      const float bv = bias[colbase + cc];
#pragma unroll
      for (int i = 0; i < 4; ++i) {
        const int rowbase = bm + wr * 64 + i * 16 + 4 * gg;
        const int b = rowbase >> 11, ll = rowbase & 2047;
        const size_t bh32 = (size_t)(b * H_N + h) * 32;
        if (type == 0) {
#pragma unroll
          for (int r = 0; r < 4; ++r)
            Qo[((size_t)(b * H_N + h) * L_SEQ + ll + r) * DK + d] =
                f2bf(acc[i][j][r] + bv);
        } else if (type == 1) {
#pragma unroll
          for (int r = 0; r < 4; ++r) {
            const int jg = ll + r;
            Ko[(bh32 + (jg >> 6)) * 4096 + (jg & 63) * 64 +
               (((d >> 3) ^ (jg & 7)) << 3) + (d & 7)] =
                f2bf(acc[i][j][r] + bv);
          }
        } else {
          ushort4 pk;
          pk.x = f2bf(acc[i][j][0] + bv);
          pk.y = f2bf(acc[i][j][1] + bv);
          pk.z = f2bf(acc[i][j][2] + bv);
          pk.w = f2bf(acc[i][j][3] + bv);
          const size_t idx = (bh32 + (ll >> 6)) * 4096 + (size_t)d * 64 +
                             ((((ll & 63) >> 3) ^ (d & 7)) << 3) + (ll & 7);
          *reinterpret_cast<ushort4*>(&Vto[idx]) = pk;
        }
      }
    }
  } else {
#pragma unroll
    for (int j = 0; j < 4; ++j) {
      const int col = bn + wc * 64 + j * 16 + cc;
      const float bv = bias[col];
#pragma unroll
      for (int i = 0; i < 4; ++i) {
        const int rowbase = bm + wr * 64 + i * 16 + 4 * gg;
#pragma unroll
        for (int r = 0; r < 4; ++r) {
          const size_t off = (size_t)(rowbase + r) * N + col;
          outF[off] = acc[i][j][r] + bv + resid[off];
        }
      }
    }
  }
}

// ---------------------------------------------- attention core (bf16 MFMA)
// 1024 blocks x 128 thr (2 waves; each wave owns TWO 16-row q-subtiles =
// 32 q-rows; block covers the same 64-row q-tile as R7). Same id->(bh,qt)
// map (XCD pin + heavy-first) and same K/V LDS DMA double-buffer.
// KEY CHANGE vs R7: K/V fragments are read from LDS ONCE per wave and fed
// to BOTH subtiles' MFMAs -> per-CU K/V LDS read traffic halves (was the
// most-loaded pipe at ~74%). TLP drops to 2 waves/SIMD but each wave now
// carries two independent softmax/PV chains (ILP substitutes TLP).
#define STAGE(buf, tile)                                                   \
  {                                                                        \
    const ushort* kg_ = KoB + (size_t)(tile) * 4096 + w * 512 + lane * 8;  \
    const ushort* vg_ = VtB + (size_t)(tile) * 4096 + w * 512 + lane * 8;  \
    _Pragma("unroll")                                                      \
    for (int r_ = 0; r_ < 4; ++r_) {                                       \
      gload_lds16(kg_ + r_ * 1024, &Ks[buf][r_ * 1024 + w * 512]);         \
      gload_lds16(vg_ + r_ * 1024, &Vs[buf][r_ * 1024 + w * 512]);         \
    }                                                                      \
  }

__global__ __launch_bounds__(128, 2) void attn_mfma(
    const ushort* __restrict__ Q, const ushort* __restrict__ Ko,
    const ushort* __restrict__ Vt, ushort* __restrict__ attn_out) {
  __shared__ ushort Ks[2][4096];
  __shared__ ushort Vs[2][4096];
  __shared__ ushort Pw_s[2][2][1024];
  const int id = blockIdx.x;
  const int bh = (id & 7) + 8 * ((id >> 3) & 3);
  const int qt = 31 - (id >> 5);
  const int tid = threadIdx.x;
  const int w = tid >> 6, lane = tid & 63;
  const int c = lane & 15, g = lane >> 4;
  const int b = bh >> 3, h = bh & 7;
  const ushort* KoB = Ko + (size_t)bh * 32 * 4096;
  const ushort* VtB = Vt + (size_t)bh * 32 * 4096;
  const int q00 = qt * 64 + w * 32;     // subtile 0: rows q00..q00+15
  const int q01 = q00 + 16;             // subtile 1: rows q01..q01+15
  const int pc0 = (g ^ (c & 7)) * 8;
  const int pc1 = ((g + 4) ^ (c & 7)) * 8;

  bf16x8 qA0[2], qA1[2];
  {
    const ushort* qp0 = Q + ((size_t)bh * L_SEQ + q00 + c) * DK + g * 8;
    qA0[0] = *reinterpret_cast<const bf16x8*>(qp0);
    qA0[1] = *reinterpret_cast<const bf16x8*>(qp0 + 32);
    const ushort* qp1 = Q + ((size_t)bh * L_SEQ + q01 + c) * DK + g * 8;
    qA1[0] = *reinterpret_cast<const bf16x8*>(qp1);
    qA1[1] = *reinterpret_cast<const bf16x8*>(qp1 + 32);
  }

  f32x4 O0[4] = {}, O1[4] = {};
  float m0[4] = {-INFINITY, -INFINITY, -INFINITY, -INFINITY};
  float m1[4] = {-INFINITY, -INFINITY, -INFINITY, -INFINITY};
  float ls0[4] = {}, ls1[4] = {};
  const f32x4 zero4 = {0.f, 0.f, 0.f, 0.f};

  STAGE(0, 0);
  __syncthreads();

  for (int jt = 0; jt <= qt; ++jt) {
    const int cur = jt & 1;
    if (jt < qt) STAGE(cur ^ 1, jt + 1);
    const ushort* Kc = Ks[cur];
    const ushort* Vc = Vs[cur];
    const int j0 = jt * 64;
    // ---- QK^T from LDS: K-frags read ONCE, used by both subtiles
    f32x4 S0[4], S1[4];
#pragma unroll
    for (int n = 0; n < 4; ++n) {
      const bf16x8 k0 = *reinterpret_cast<const bf16x8*>(&Kc[(n * 16 + c) * 64 + pc0]);
      const bf16x8 k1 = *reinterpret_cast<const bf16x8*>(&Kc[(n * 16 + c) * 64 + pc1]);
      S0[n] = __builtin_amdgcn_mfma_f32_16x16x32_bf16(qA0[0], k0, zero4, 0, 0, 0);
      S0[n] = __builtin_amdgcn_mfma_f32_16x16x32_bf16(qA0[1], k1, S0[n], 0, 0, 0);
      S1[n] = __builtin_amdgcn_mfma_f32_16x16x32_bf16(qA1[0], k0, zero4, 0, 0, 0);
      S1[n] = __builtin_amdgcn_mfma_f32_16x16x32_bf16(qA1[1], k1, S1[n], 0, 0, 0);
    }
    // ---- scale + causal mask (both subtiles)
    const bool diag = (jt == qt);
#pragma unroll
    for (int n = 0; n < 4; ++n)
#pragma unroll
      for (int r = 0; r < 4; ++r) {
        float v0 = S0[n][r] * SCALE;
        float v1 = S1[n][r] * SCALE;
        if (diag) {
          const int jm = j0 + n * 16 + c;
          if (jm > (q00 + 4 * g + r)) v0 = -INFINITY;
          if (jm > (q01 + 4 * g + r)) v1 = -INFINITY;
        }
        S0[n][r] = v0;
        S1[n][r] = v1;
      }
    // ---- defer-max test (lane-local, both subtiles share one __any)
    float pm0[4], pm1[4];
    int exceed = 0;
#pragma unroll
    for (int r = 0; r < 4; ++r) {
      pm0[r] = fmaxf(fmaxf(S0[0][r], S0[1][r]), fmaxf(S0[2][r], S0[3][r]));
      pm1[r] = fmaxf(fmaxf(S1[0][r], S1[1][r]), fmaxf(S1[2][r], S1[3][r]));
      exceed |= (pm0[r] > m0[r] + DEFER_THR) | (pm1[r] > m1[r] + DEFER_THR);
    }
    if (__any(exceed)) {
#pragma unroll
      for (int r = 0; r < 4; ++r) {
        float fm = pm0[r];
        fm = fmaxf(fm, __shfl_xor(fm, 1, 16));
        fm = fmaxf(fm, __shfl_xor(fm, 2, 16));
        fm = fmaxf(fm, __shfl_xor(fm, 4, 16));
        fm = fmaxf(fm, __shfl_xor(fm, 8, 16));
        const float mnew = fmaxf(m0[r], fm);
        const float corr = __expf(m0[r] - mnew);
        ls0[r] *= corr;
#pragma unroll
        for (int t = 0; t < 4; ++t) O0[t][r] *= corr;
        m0[r] = mnew;
      }
#pragma unroll
      for (int r = 0; r < 4; ++r) {
        float fm = pm1[r];
        fm = fmaxf(fm, __shfl_xor(fm, 1, 16));
        fm = fmaxf(fm, __shfl_xor(fm, 2, 16));
        fm = fmaxf(fm, __shfl_xor(fm, 4, 16));
        fm = fmaxf(fm, __shfl_xor(fm, 8, 16));
        const float mnew = fmaxf(m1[r], fm);
        const float corr = __expf(m1[r] - mnew);
        ls1[r] *= corr;
#pragma unroll
        for (int t = 0; t < 4; ++t) O1[t][r] *= corr;
        m1[r] = mnew;
      }
    }
    // ---- P = exp(S - m), lane partials (both subtiles)
#pragma unroll
    for (int n = 0; n < 4; ++n)
#pragma unroll
      for (int r = 0; r < 4; ++r) {
        const float p0 = __expf(S0[n][r] - m0[r]);
        const float p1 = __expf(S1[n][r] - m1[r]);
        S0[n][r] = p0; ls0[r] += p0;
        S1[n][r] = p1; ls1[r] += p1;
      }
    // ---- P -> bf16 LDS re-layout (per-wave, per-subtile buffers)
    ushort* Pw0 = Pw_s[w][0];
    ushort* Pw1 = Pw_s[w][1];
#pragma unroll
    for (int n = 0; n < 4; ++n)
#pragma unroll
      for (int r = 0; r < 4; ++r) {
        const int row = 4 * g + r;
        const int off = row * 64 + ((2 * n + (c >> 3)) ^ (row & 7)) * 8 + (c & 7);
        Pw0[off] = f2bf(S0[n][r]);
        Pw1[off] = f2bf(S1[n][r]);
      }
    const bf16x8 pA00 = *reinterpret_cast<const bf16x8*>(&Pw0[c * 64 + pc0]);
    const bf16x8 pA01 = *reinterpret_cast<const bf16x8*>(&Pw0[c * 64 + pc1]);
    const bf16x8 pA10 = *reinterpret_cast<const bf16x8*>(&Pw1[c * 64 + pc0]);
    const bf16x8 pA11 = *reinterpret_cast<const bf16x8*>(&Pw1[c * 64 + pc1]);
    // ---- PV from LDS: V-frags read ONCE, used by both subtiles
#pragma unroll
    for (int t = 0; t < 4; ++t) {
      const bf16x8 v0 = *reinterpret_cast<const bf16x8*>(&Vc[(t * 16 + c) * 64 + pc0]);
      const bf16x8 v1 = *reinterpret_cast<const bf16x8*>(&Vc[(t * 16 + c) * 64 + pc1]);
      O0[t] = __builtin_amdgcn_mfma_f32_16x16x32_bf16(pA00, v0, O0[t], 0, 0, 0);
      O0[t] = __builtin_amdgcn_mfma_f32_16x16x32_bf16(pA01, v1, O0[t], 0, 0, 0);
      O1[t] = __builtin_amdgcn_mfma_f32_16x16x32_bf16(pA10, v0, O1[t], 0, 0, 0);
      O1[t] = __builtin_amdgcn_mfma_f32_16x16x32_bf16(pA11, v1, O1[t], 0, 0, 0);
    }
    __syncthreads();  // drains prefetch DMA; both waves done with buf cur
  }
  // ---- final row-sum reductions + normalize + store (both subtiles)
  float inv0[4], inv1[4];
#pragma unroll
  for (int r = 0; r < 4; ++r) {
    float s = ls0[r];
    s += __shfl_xor(s, 1, 16);
    s += __shfl_xor(s, 2, 16);
    s += __shfl_xor(s, 4, 16);
    s += __shfl_xor(s, 8, 16);
    inv0[r] = 1.f / s;
    float t = ls1[r];
    t += __shfl_xor(t, 1, 16);
    t += __shfl_xor(t, 2, 16);
    t += __shfl_xor(t, 4, 16);
    t += __shfl_xor(t, 8, 16);
    inv1[r] = 1.f / t;
  }
#pragma unroll
  for (int t = 0; t < 4; ++t)
#pragma unroll
    for (int r = 0; r < 4; ++r) {
      attn_out[((size_t)b * L_SEQ + q00 + 4 * g + r) * C_DIM + h * DK + t * 16 + c] =
          f2bf(O0[t][r] * inv0[r]);
      attn_out[((size_t)b * L_SEQ + q01 + 4 * g + r) * C_DIM + h * DK + t * 16 + c] =
          f2bf(O1[t][r] * inv1[r]);
    }
}

// ------------------------------------------------------------------- launch
extern "C" void kernel_launch(void* const* d_in, const int* in_sizes, int n_in,
                              void* d_out, int out_size, void* d_ws,
                              size_t ws_size, hipStream_t stream) {
  const float* x     = (const float*)d_in[0];
  const float* W_in  = (const float*)d_in[1];
  const float* b_in  = (const float*)d_in[2];
  const float* W_out = (const float*)d_in[3];
  const float* b_out = (const float*)d_in[4];
  float* out = (float*)d_out;

  ushort* xbf   = (ushort*)d_ws;                       // 8192x512
  ushort* WinT  = xbf + (size_t)M_ROWS * C_DIM;        // 1536x512
  ushort* WoutT = WinT + (size_t)N_QKV * C_DIM;        // 512x512
  ushort* Qo    = WoutT + (size_t)C_DIM * C_DIM;       // [BH,L,64]
  ushort* Ko    = Qo + (size_t)M_ROWS * C_DIM;         // [BH,32 tiles,4096]
  ushort* Vto   = Ko + (size_t)M_ROWS * C_DIM;         // [BH,32 tiles,4096]
  ushort* attnb = Vto + (size_t)M_ROWS * C_DIM;        // [8192,512]

  prep_fused<<<dim3(4352, 1, 1), 256, 0, stream>>>(
      x, W_in, W_out, xbf, WinT, WoutT);
  gemm_bf16<0><<<dim3(N_QKV / 128, M_ROWS / 128), 256, 0, stream>>>(
      xbf, WinT, b_in, Qo, Ko, Vto, nullptr, nullptr, N_QKV, C_DIM);
  attn_mfma<<<dim3(1024, 1, 1), 128, 0, stream>>>(Qo, Ko, Vto, attnb);
  gemm_bf16<1><<<dim3(C_DIM / 128, M_ROWS / 128), 256, 0, stream>>>(
      attnb, WoutT, b_out, nullptr, nullptr, nullptr, out, x, C_DIM, C_DIM);
}